// Round 1
// baseline (129.507 us; speedup 1.0000x reference)
//
#include <hip/hip_runtime.h>

#define B_DIM 32
#define T_DIM 512
#define D_DIM 256
#define U_DIM 1024
#define M_DIM (B_DIM * T_DIM)  // 16384

typedef __bf16 bf16_t;
typedef bf16_t bf16x8 __attribute__((ext_vector_type(8)));
typedef float f32x4 __attribute__((ext_vector_type(4)));

__device__ __forceinline__ float ssign(float z) {
    return z * __builtin_amdgcn_rcpf(1.0f + __builtin_fabsf(z));
}

// ---------------- prep: W transpose+cast, X cast, H0/drive GEMV — one dispatch -------
// blocks [0,64):      Wd f32 [K=256][N=1024] -> Wt bf16 [N][K]
// blocks [64,2112):   Xts f32 [M][K] -> Xb bf16 [M][K]
// blocks [2112,2240): H0/drive per (b,u): coalesced-across-u GEMV (was a ~5us
//                     latency-serial per-lane strided loop inside the fused kernel)
__global__ __launch_bounds__(256) void prep(const float* __restrict__ Wd,
                                            bf16_t* __restrict__ Wt,
                                            const float* __restrict__ X,
                                            bf16_t* __restrict__ Xb,
                                            const float* __restrict__ Xv,
                                            const float* __restrict__ A0,
                                            const float* __restrict__ b0,
                                            const float* __restrict__ As,
                                            const float* __restrict__ bs,
                                            const float* __restrict__ bd,
                                            float* __restrict__ H0o,
                                            float* __restrict__ Dro) {
    const int bid = blockIdx.x;
    if (bid < 64) {
        __shared__ float tile[64][65];
        const int tx = threadIdx.x & 63;
        const int ty = threadIdx.x >> 6;  // 0..3
        const int n0 = (bid & 15) * 64;
        const int k0 = (bid >> 4) * 64;
        #pragma unroll
        for (int rr = 0; rr < 16; ++rr) {
            const int kk = ty * 16 + rr;
            tile[kk][tx] = Wd[(size_t)(k0 + kk) * U_DIM + n0 + tx];
        }
        __syncthreads();
        #pragma unroll
        for (int rr = 0; rr < 16; ++rr) {
            const int nn = ty * 16 + rr;
            Wt[(size_t)(n0 + nn) * D_DIM + k0 + tx] = (bf16_t)tile[tx][nn];
        }
    } else if (bid < 2112) {
        const int i = ((bid - 64) * 256 + threadIdx.x) * 8;
        const float4 a = *(const float4*)(X + i);
        const float4 b = *(const float4*)(X + i + 4);
        bf16x8 p;
        p[0]=(bf16_t)a.x; p[1]=(bf16_t)a.y; p[2]=(bf16_t)a.z; p[3]=(bf16_t)a.w;
        p[4]=(bf16_t)b.x; p[5]=(bf16_t)b.y; p[6]=(bf16_t)b.z; p[7]=(bf16_t)b.w;
        *(bf16x8*)(Xb + i) = p;
    } else {
        // H0 = ssign(Xv@A0 + b0), drive = Xv@As + bs + bd  — 128 blocks = 32b x 4 u-tiles
        __shared__ float xv[D_DIM];
        const int idx = bid - 2112;
        const int b = idx >> 2;
        const int u = (idx & 3) * 256 + threadIdx.x;
        xv[threadIdx.x] = Xv[(size_t)b * D_DIM + threadIdx.x];
        __syncthreads();
        float a0 = 0.f, asum = 0.f;
        #pragma unroll 8
        for (int d = 0; d < D_DIM; ++d) {
            const float x = xv[d];
            a0   = fmaf(x, A0[(size_t)d * U_DIM + u], a0);
            asum = fmaf(x, As[(size_t)d * U_DIM + u], asum);
        }
        H0o[(size_t)b * U_DIM + u] = ssign(a0 + b0[u]);
        Dro[(size_t)b * U_DIM + u] = asum + bs[u] + bd[u];
    }
}

// ---------------- Fused GEMM+scan: producer/consumer wave pair -----------------------
// 2 waves/block. Wave1 (producer): MFMA chunk c+2 -> LDS ring[4], A-frags prefetched
// 2 chunks (~1000cy) ahead of use; NO stores -> its vmcnt queue is loads-only, waits
// stay counted. Wave0 (consumer): issues next-chunk ds_reads BEFORE running the
// 16-step softsign chain on current regs (LDS latency hidden), streamed 256B stores;
// NO loads -> stores never forced to drain. Sync = raw s_barrier + lgkmcnt(0) only
// (NOT __syncthreads: that emits vmcnt(0) and drains the store queue every chunk).
// 4 waves/CU (vs 2 before), and each wave's stalls are the other's overlap.
__global__ __launch_bounds__(128, 1) void fused3(
        const float* __restrict__ H0w, const float* __restrict__ Drw,
        const bf16_t* __restrict__ Xb, const bf16_t* __restrict__ Wt,
        float* __restrict__ out) {
    __shared__ float xwT[4][64 * 20];  // ring of 4 chunk buffers, rows padded to 20 f32

    const int lane = threadIdx.x & 63;
    const int wid = threadIdx.x >> 6;
    const int b = blockIdx.x;
    const int u0 = blockIdx.y * 64;

#define BARX()                                                          \
    do {                                                                \
        __asm__ volatile("s_waitcnt lgkmcnt(0)" ::: "memory");          \
        __builtin_amdgcn_s_barrier();                                   \
        __asm__ volatile("" ::: "memory");                              \
    } while (0)

    if (wid == 1) {
        // ---------------- producer ----------------
        const int lm = lane & 15, q = lane >> 4;
        const bf16_t* xrow = Xb + ((size_t)b * T_DIM + lm) * D_DIM + q * 8;

#define LOADA(DST, CH)                                                              \
    {                                                                               \
        const bf16_t* xp_ = xrow + (size_t)(CH) * 16 * D_DIM;                       \
        _Pragma("unroll")                                                           \
        for (int kb = 0; kb < 8; ++kb) DST[kb] = *(const bf16x8*)(xp_ + kb * 32);   \
    }

        bf16x8 af0[8], af1[8], af2[8], af3[8];
        LOADA(af0, 0); LOADA(af1, 1); LOADA(af2, 2); LOADA(af3, 3);

        bf16x8 bW[4][8];
        #pragma unroll
        for (int n = 0; n < 4; ++n)
            #pragma unroll
            for (int kb = 0; kb < 8; ++kb)
                bW[n][kb] = *(const bf16x8*)(Wt + (size_t)(u0 + n * 16 + lm) * D_DIM + kb * 32 + q * 8);

        f32x4 acc[4];
#define ZACC()                                                                      \
    {                                                                               \
        _Pragma("unroll")                                                           \
        for (int n = 0; n < 4; ++n) acc[n] = (f32x4){0.f, 0.f, 0.f, 0.f};           \
    }
#define MM(AF)                                                                      \
    {                                                                               \
        _Pragma("unroll")                                                           \
        for (int kb = 0; kb < 8; ++kb) {                                            \
            _Pragma("unroll")                                                       \
            for (int n = 0; n < 4; ++n)                                             \
                acc[n] = __builtin_amdgcn_mfma_f32_16x16x32_bf16(AF[kb], bW[n][kb], \
                                                                 acc[n], 0, 0, 0);  \
        }                                                                           \
    }
#define STASHS(SLOT)                                                                \
    {                                                                               \
        _Pragma("unroll")                                                           \
        for (int n = 0; n < 4; ++n)                                                 \
            *(f32x4*)&xwT[SLOT][(n * 16 + lm) * 20 + q * 4] = acc[n];               \
    }

        // prologue: chunks 0,1 into ring slots 0,1
        ZACC(); MM(af0); STASHS(0);
        ZACC(); MM(af1); STASHS(1);
        BARX();  // #1: slots 0,1 ready

        // iter c produces chunk c+2 into slot (c+2)&3; loads chunk c+4 into the
        // slot just freed (af regs static-indexed via 4x unrolled body, rule #20)
        #pragma unroll 1
        for (int cc = 0; cc < 32; cc += 4) {
            if (cc + 2 < 32) { if (cc + 4 < 32) LOADA(af0, cc + 4);
                               ZACC(); MM(af2); STASHS(2); }
            BARX();
            if (cc + 3 < 32) { if (cc + 5 < 32) LOADA(af1, cc + 5);
                               ZACC(); MM(af3); STASHS(3); }
            BARX();
            if (cc + 4 < 32) { if (cc + 6 < 32) LOADA(af2, cc + 6);
                               ZACC(); MM(af0); STASHS(0); }
            BARX();
            if (cc + 5 < 32) { if (cc + 7 < 32) LOADA(af3, cc + 7);
                               ZACC(); MM(af1); STASHS(1); }
            BARX();
        }
#undef LOADA
#undef ZACC
#undef MM
#undef STASHS
    } else {
        // ---------------- consumer ----------------
        const int u = u0 + lane;
        float h = H0w[(size_t)b * U_DIM + u];
        const float drive = Drw[(size_t)b * U_DIM + u];
        float* po = out + (size_t)b * T_DIM * U_DIM + u;

        BARX();  // #1: slot 0 ready
        const float* rb0 = &xwT[0][lane * 20];
        f32x4 v0 = *(const f32x4*)(rb0 + 0);
        f32x4 v1 = *(const f32x4*)(rb0 + 4);
        f32x4 v2 = *(const f32x4*)(rb0 + 8);
        f32x4 v3 = *(const f32x4*)(rb0 + 12);

        #pragma unroll 1
        for (int c = 0; c < 32; ++c) {
            // issue next-chunk ds_reads first: slot (c+1)&3 was ready at the
            // previous barrier; latency hides under the 16-step chain below.
            // (c=31 reads stale slot 0 — values discarded, no race: producer
            // stopped writing after chunk 31.)
            const float* rbn = &xwT[(c + 1) & 3][lane * 20];
            f32x4 n0 = *(const f32x4*)(rbn + 0);
            f32x4 n1 = *(const f32x4*)(rbn + 4);
            f32x4 n2 = *(const f32x4*)(rbn + 8);
            f32x4 n3 = *(const f32x4*)(rbn + 12);

            float dv[16];
            #pragma unroll
            for (int r = 0; r < 4; ++r) {
                dv[r]      = drive + v0[r];
                dv[4 + r]  = drive + v1[r];
                dv[8 + r]  = drive + v2[r];
                dv[12 + r] = drive + v3[r];
            }
            #pragma unroll
            for (int j = 0; j < 16; ++j) {
                h = ssign(h + dv[j]);
                po[(size_t)(c * 16 + j) * U_DIM] = h;
            }
            BARX();
            v0 = n0; v1 = n1; v2 = n2; v3 = n3;
        }
    }
#undef BARX
}

// ---------------- Fallback (tiny ws): f32 path (proven round-2) ----------------------
__global__ __launch_bounds__(256) void gemm_xw_f32(const float* __restrict__ Xts,
                                                   const float* __restrict__ Wd,
                                                   float* __restrict__ out) {
    __shared__ float xs[16 * D_DIM];
    const int tid = threadIdx.x;
    const int bt0 = blockIdx.y * 16;
    const int u = blockIdx.x * 256 + tid;
    const float4* src4 = (const float4*)(Xts + (size_t)bt0 * D_DIM);
    float4* xs4 = (float4*)xs;
    #pragma unroll
    for (int i = 0; i < 4; ++i) xs4[tid + 256 * i] = src4[tid + 256 * i];
    __syncthreads();
    float acc[16];
    #pragma unroll
    for (int r = 0; r < 16; ++r) acc[r] = 0.0f;
    const float* wp = Wd + u;
    for (int d0 = 0; d0 < D_DIM; d0 += 4) {
        const float w0 = wp[(size_t)(d0 + 0) * U_DIM];
        const float w1 = wp[(size_t)(d0 + 1) * U_DIM];
        const float w2 = wp[(size_t)(d0 + 2) * U_DIM];
        const float w3 = wp[(size_t)(d0 + 3) * U_DIM];
        #pragma unroll
        for (int r = 0; r < 16; ++r) {
            const float4 xvv = *(const float4*)&xs[r * D_DIM + d0];
            acc[r] = fmaf(xvv.x, w0, acc[r]);
            acc[r] = fmaf(xvv.y, w1, acc[r]);
            acc[r] = fmaf(xvv.z, w2, acc[r]);
            acc[r] = fmaf(xvv.w, w3, acc[r]);
        }
    }
    #pragma unroll
    for (int r = 0; r < 16; ++r)
        out[(size_t)(bt0 + r) * U_DIM + u] = acc[r];
}

__global__ __launch_bounds__(256) void scan_old(const float* __restrict__ Xv,
                                                const float* __restrict__ A0,
                                                const float* __restrict__ b0,
                                                const float* __restrict__ As,
                                                const float* __restrict__ bs,
                                                const float* __restrict__ bd,
                                                float* __restrict__ out) {
    __shared__ float xv[D_DIM];
    const int tid = threadIdx.x;
    const int b = blockIdx.y;
    const int u = blockIdx.x * 256 + tid;
    xv[tid] = Xv[(size_t)b * D_DIM + tid];
    __syncthreads();
    float a0 = 0.0f, asum = 0.0f;
    #pragma unroll 4
    for (int d = 0; d < D_DIM; ++d) {
        const float x = xv[d];
        a0   = fmaf(x, A0[(size_t)d * U_DIM + u], a0);
        asum = fmaf(x, As[(size_t)d * U_DIM + u], asum);
    }
    a0 += b0[u];
    const float drive = asum + bs[u] + bd[u];
    float h = ssign(a0);
    float* po = out + (size_t)b * T_DIM * U_DIM + u;
    float buf[8];
    #pragma unroll
    for (int i = 0; i < 8; ++i) buf[i] = po[(size_t)i * U_DIM];
    for (int t = 0; t < T_DIM; t += 8) {
        #pragma unroll
        for (int i = 0; i < 8; ++i) {
            const float x = buf[i];
            const int tn = t + i + 8;
            if (tn < T_DIM) buf[i] = po[(size_t)tn * U_DIM];
            h = ssign(h + drive + x);
            po[(size_t)(t + i) * U_DIM] = h;
        }
    }
}

extern "C" void kernel_launch(void* const* d_in, const int* in_sizes, int n_in,
                              void* d_out, int out_size, void* d_ws, size_t ws_size,
                              hipStream_t stream) {
    const float* Xv  = (const float*)d_in[0];
    const float* Xts = (const float*)d_in[1];
    const float* A0  = (const float*)d_in[2];
    const float* b0  = (const float*)d_in[3];
    const float* As  = (const float*)d_in[4];
    const float* bs  = (const float*)d_in[5];
    const float* Wd  = (const float*)d_in[6];
    const float* bd  = (const float*)d_in[7];
    float* out = (float*)d_out;

    // ws layout: Wt bf16 [0,512K) | H0 f32 [512K,640K) | Dr f32 [640K,768K) | Xb bf16 [1M,9M)
    const size_t OFF_H0 = 512u << 10;
    const size_t OFF_DR = 640u << 10;
    const size_t OFF_XB = 1u << 20;
    const size_t NEED   = 16u << 20;

    if (ws_size >= NEED) {
        bf16_t* Wt = (bf16_t*)d_ws;
        float* H0w = (float*)((char*)d_ws + OFF_H0);
        float* Drw = (float*)((char*)d_ws + OFF_DR);
        bf16_t* Xb = (bf16_t*)((char*)d_ws + OFF_XB);
        prep<<<dim3(64 + M_DIM * D_DIM / (256 * 8) + 128), dim3(256), 0, stream>>>(
            Wd, Wt, Xts, Xb, Xv, A0, b0, As, bs, bd, H0w, Drw);
        fused3<<<dim3(B_DIM, U_DIM / 64), dim3(128), 0, stream>>>(H0w, Drw, Xb, Wt, out);
    } else {
        gemm_xw_f32<<<dim3(U_DIM / 256, M_DIM / 16), dim3(256), 0, stream>>>(Xts, Wd, out);
        scan_old<<<dim3(U_DIM / 256, B_DIM), dim3(256), 0, stream>>>(Xv, A0, b0, As, bs, bd, out);
    }
}